// Round 16
// baseline (82.565 us; speedup 1.0000x reference)
//
#include <hip/hip_runtime.h>
#include <cstdint>
#include <cstddef>
#include <math.h>

#define B 16
#define S 200
#define D 128
#define VOCAB 100000
#define V4 (VOCAB / 4)                 // 25000 float4 columns
#define SCH 8
#define VTILE 256                      // vocab words per block
#define NBLK ((VOCAB + VTILE - 1) / VTILE)   // 391

// K1: attention scores: per block = one (b, chunk of 8 s). 128 threads (one per e-dim).
__global__ __launch_bounds__(128) void k_scores(
    const float* __restrict__ x,
    const float* __restrict__ Wq, const float* __restrict__ bq,
    const float* __restrict__ Wk, const float* __restrict__ bk,
    const float* __restrict__ Wv, const float* __restrict__ bv,
    float* __restrict__ scores)
{
  const int b  = blockIdx.x / (S / SCH);
  const int s0 = (blockIdx.x % (S / SCH)) * SCH;
  const int e  = threadIdx.x;

  __shared__ float lx[SCH][D];
  __shared__ float l0[D];
  __shared__ float sred[2][SCH];

  l0[e] = x[(size_t)b * S * D + e];
  #pragma unroll
  for (int i = 0; i < SCH; i++) lx[i][e] = x[((size_t)b * S + s0 + i) * D + e];
  __syncthreads();

  float q[SCH];
  const float bqe = bq[e];
  #pragma unroll
  for (int i = 0; i < SCH; i++) q[i] = bqe;
  float kk = bk[e];

  for (int d = 0; d < D; d++) {
    const float wq = Wq[d * D + e];
    const float wk = Wk[d * D + e];
    const float x0 = l0[d];
    kk += x0 * wk;
    #pragma unroll
    for (int i = 0; i < SCH; i++) q[i] += lx[i][d] * wq;
  }

  const float wv  = Wv[e];
  const float bv0 = bv[0];
  #pragma unroll
  for (int i = 0; i < SCH; i++) {
    float val = tanhf(q[i] + kk) * wv;
    #pragma unroll
    for (int off = 32; off > 0; off >>= 1) val += __shfl_down(val, off, 64);
    if ((e & 63) == 0) sred[e >> 6][i] = val;
  }
  __syncthreads();
  if (e < SCH) scores[b * S + s0 + e] = sred[0][e] + sred[1][e] + bv0;
}

// K2: softmax over S + c_s; 512 threads: 4 s-splits x 128 d.
// Writes cvec[dd*16 + b], dd 0..255 (h_t | c_s).
__global__ __launch_bounds__(512) void k_csum(
    const float* __restrict__ x, const float* __restrict__ scores,
    float* __restrict__ cvec)
{
  const int b = blockIdx.x;
  const int t = threadIdx.x;
  __shared__ float pr[S];
  __shared__ float redm[9];
  __shared__ float reds[9];
  __shared__ float cpart[3][D];

  float v = (t < S) ? scores[b * S + t] : -INFINITY;
  float m = v;
  #pragma unroll
  for (int off = 32; off > 0; off >>= 1) m = fmaxf(m, __shfl_down(m, off, 64));
  if ((t & 63) == 0) redm[t >> 6] = m;
  __syncthreads();
  if (t == 0) {
    float mm = redm[0];
    #pragma unroll
    for (int i = 1; i < 8; i++) mm = fmaxf(mm, redm[i]);
    redm[8] = mm;
  }
  __syncthreads();
  const float mx = redm[8];

  float e = (t < S) ? expf(v - mx) : 0.f;
  float s = e;
  #pragma unroll
  for (int off = 32; off > 0; off >>= 1) s += __shfl_down(s, off, 64);
  if ((t & 63) == 0) reds[t >> 6] = s;
  __syncthreads();
  if (t == 0) {
    float ss = 0.f;
    #pragma unroll
    for (int i = 0; i < 8; i++) ss += reds[i];
    reds[8] = ss;
  }
  __syncthreads();
  const float inv = 1.0f / reds[8];
  if (t < S) pr[t] = e * inv;
  __syncthreads();

  const int d = t & 127;
  const int sq = t >> 7;
  float acc = 0.f;
  const float* xb = x + ((size_t)b * S + sq * 50) * D + d;
  #pragma unroll 5
  for (int s2 = 0; s2 < 50; s2++) acc += pr[sq * 50 + s2] * xb[s2 * D];
  if (sq) cpart[sq - 1][d] = acc;
  __syncthreads();
  if (sq == 0) {
    cvec[d * B + b]       = x[(size_t)b * S * D + d];
    cvec[(D + d) * B + b] = acc + cpart[0][d] + cpart[1][d] + cpart[2][d];
  }
}

// K3: fused gemv + bias + mask + exp + per-block partial sums.
// R16 "b-split" design, from R14/R15 measurements:
//   - W delivery copies k_stream_reg verbatim (16 float4 loads batched, THEN
//     use; measured 23.5 TB/s at this exact grid/occupancy). No interleaved
//     pipeline the scheduler can sink; no DMA (7 TB/s cap); no scalar-c.
//   - Wave bq owns b in [bq*4, bq*4+4), ALL 256 d: acc = 4 float4 = 16 VGPR,
//     so w[16] (64 VGPR) + acc + addr ~= 95 fits the (256,4) 128-VGPR cap --
//     the R15 re-roll (VGPR=84 < needed 128+) cannot recur.
//   - Cost: 4x W re-read (391 MB, all L3-resident) ~= 17 us -- the new floor.
//   - c: ONE broadcast ds_read_b128 per d-row (vs 16 in R11).
//   - Zero cross-wave combine: no RED buffer, no epilogue barriers.
//   - Full float4 stores: kills R15's 3.2x write amplification.
__global__ __launch_bounds__(256, 4) void k_gemv(
    const float* __restrict__ cvec, const float* __restrict__ Wec,
    const float* __restrict__ bec, const int* __restrict__ ids,
    float* __restrict__ out, float* __restrict__ partial)
{
  __shared__ __align__(16) float cl[256 * 16];   // [256 d][16 b] staged c (16 KB)
  __shared__ unsigned mbit[B * 8];               // 16 b x 256 v bits

  const int t    = threadIdx.x;
  const int lane = t & 63;
  const int bq   = t >> 6;                       // wave's b-quarter

  // stage c once (coalesced float4)
  {
    const float4* src = (const float4*)cvec;
    float4* dst = (float4*)cl;
    #pragma unroll
    for (int i = 0; i < 4; i++) dst[t + 256 * i] = src[t + 256 * i];
  }
  if (t < B * 8) mbit[t] = 0u;

  const int vbase = blockIdx.x * VTILE;
  const int v4    = blockIdx.x * 64 + lane;      // this thread's float4 column
  const bool valid = (v4 < V4);
  const int v4c   = valid ? v4 : (V4 - 1);

  const float4* wp = (const float4*)Wec + v4c;   // row stride V4

  // build mask bitmap for this block's v-range
  for (int i = t; i < B * S; i += 256) {
    const int id = ids[i];
    if (id > 1 && id >= vbase && id < vbase + VTILE) {
      const int lv = id - vbase;
      atomicOr(&mbit[(i / S) * 8 + (lv >> 5)], 1u << (lv & 31));
    }
  }
  __syncthreads();     // cl + mbit ready; the only barrier in this kernel

  float4 acc[4];
  #pragma unroll
  for (int i = 0; i < 4; i++) acc[i] = make_float4(0.f, 0.f, 0.f, 0.f);

  // k_stream_reg pattern: 16 chunks x {16 batched loads -> 16 uses}
  for (int c = 0; c < 16; c++) {
    float4 w[16];
    #pragma unroll
    for (int j = 0; j < 16; j++)
      w[j] = wp[(size_t)(c * 16 + j) * V4];
    #pragma unroll
    for (int j = 0; j < 16; j++) {
      // broadcast ds_read_b128: same address across all 64 lanes
      const float4 cb = *(const float4*)&cl[(c * 16 + j) * 16 + bq * 4];
      acc[0].x = fmaf(w[j].x, cb.x, acc[0].x);
      acc[0].y = fmaf(w[j].y, cb.x, acc[0].y);
      acc[0].z = fmaf(w[j].z, cb.x, acc[0].z);
      acc[0].w = fmaf(w[j].w, cb.x, acc[0].w);
      acc[1].x = fmaf(w[j].x, cb.y, acc[1].x);
      acc[1].y = fmaf(w[j].y, cb.y, acc[1].y);
      acc[1].z = fmaf(w[j].z, cb.y, acc[1].z);
      acc[1].w = fmaf(w[j].w, cb.y, acc[1].w);
      acc[2].x = fmaf(w[j].x, cb.z, acc[2].x);
      acc[2].y = fmaf(w[j].y, cb.z, acc[2].y);
      acc[2].z = fmaf(w[j].z, cb.z, acc[2].z);
      acc[2].w = fmaf(w[j].w, cb.z, acc[2].w);
      acc[3].x = fmaf(w[j].x, cb.w, acc[3].x);
      acc[3].y = fmaf(w[j].y, cb.w, acc[3].y);
      acc[3].z = fmaf(w[j].z, cb.w, acc[3].z);
      acc[3].w = fmaf(w[j].w, cb.w, acc[3].w);
    }
  }

  // per-wave epilogue: bias + mask + exp + full-float4 store + psum
#define MASKED(bb, lv) ((mbit[(bb) * 8 + ((lv) >> 5)] >> ((lv) & 31)) & 1u)
  const float4 be4 = ((const float4*)bec)[v4c];
  const int lv0 = lane * 4;

  #pragma unroll
  for (int i = 0; i < 4; i++) {
    const int bb = bq * 4 + i;
    float4 e = make_float4(0.f, 0.f, 0.f, 0.f);
    if (valid) {
      e.x = MASKED(bb, lv0 + 0) ? 0.f : __expf(acc[i].x + be4.x);
      e.y = MASKED(bb, lv0 + 1) ? 0.f : __expf(acc[i].y + be4.y);
      e.z = MASKED(bb, lv0 + 2) ? 0.f : __expf(acc[i].z + be4.z);
      e.w = MASKED(bb, lv0 + 3) ? 0.f : __expf(acc[i].w + be4.w);
      *(float4*)&out[(size_t)bb * VOCAB + (size_t)v4 * 4] = e;
    }
    float s = e.x + e.y + e.z + e.w;
    #pragma unroll
    for (int off = 32; off > 0; off >>= 1) s += __shfl_down(s, off, 64);
    if (lane == 0) partial[blockIdx.x * 16 + bb] = s;
  }
#undef MASKED
}

// K4: normalize; each block reduces the 391 partials for its batch inline.
__global__ __launch_bounds__(256) void k_norm(float* __restrict__ out,
                                              const float* __restrict__ partial)
{
  const int b  = blockIdx.y;
  const int t  = threadIdx.x;
  __shared__ float red[4];

  float s = 0.f;
  for (int j = t; j < NBLK; j += 256) s += partial[j * 16 + b];
  #pragma unroll
  for (int off = 32; off > 0; off >>= 1) s += __shfl_down(s, off, 64);
  if ((t & 63) == 0) red[t >> 6] = s;
  __syncthreads();
  const float iv = 1.0f / (red[0] + red[1] + red[2] + red[3]);

  const int i4 = blockIdx.x * 256 + t;
  if (i4 < V4) {
    float4* p = (float4*)out + (size_t)b * V4 + i4;
    float4 q = *p;
    q.x *= iv; q.y *= iv; q.z *= iv; q.w *= iv;
    *p = q;
  }
}

extern "C" void kernel_launch(void* const* d_in, const int* in_sizes, int n_in,
                              void* d_out, int out_size, void* d_ws, size_t ws_size,
                              hipStream_t stream)
{
  const float* x   = (const float*)d_in[0];
  const int*   ids = (const int*)d_in[1];
  const float* Wq  = (const float*)d_in[2];
  const float* bq  = (const float*)d_in[3];
  const float* Wk  = (const float*)d_in[4];
  const float* bk  = (const float*)d_in[5];
  const float* Wv  = (const float*)d_in[6];
  const float* bv  = (const float*)d_in[7];
  const float* Wec = (const float*)d_in[8];
  const float* bec = (const float*)d_in[9];
  float* out = (float*)d_out;
  float* ws  = (float*)d_ws;

  float* scores  = ws;            // 3200
  float* cvec    = ws + 3200;     // 4096  ([256][16])
  float* partial = ws + 7296;     // NBLK*16 = 6256

  k_scores <<<dim3(B * (S / SCH)), dim3(128), 0, stream>>>(x, Wq, bq, Wk, bk, Wv, bv, scores);
  k_csum   <<<dim3(B),             dim3(512), 0, stream>>>(x, scores, cvec);
  k_gemv   <<<dim3(NBLK),          dim3(256), 0, stream>>>(cvec, Wec, bec, ids, out, partial);
  k_norm   <<<dim3((V4 + 255) / 256, B), dim3(256), 0, stream>>>(out, partial);
}